// Round 4
// baseline (254.236 us; speedup 1.0000x reference)
//
#include <hip/hip_runtime.h>
#include <hip/hip_bf16.h>
#include <stdint.h>

// QuantizedLinear: out[16,11008] = x[16,4096] @ ((W - zp)*scale)^T
// HARNESS NOTE: integer inputs are materialized as int32, so W is a 180 MB
// int32 buffer. Roofline = 180 MB / 6.3 TB/s ~ 29 us. ~215 us/iter is
// harness fillBuffer resets we cannot touch; qgemm is ~36.5 us of the rest.
//
// R3 post-mortem: contiguous-1KB LDS staging gained ~7 us (47->40 our-
// portion). Remaining gap attributed to the per-chunk __syncthreads drain:
// hipcc lowers it with s_waitcnt vmcnt(0), which drains the *just-issued*
// chunk-(c+1) prefetch loads every iteration -> 16 exposed HBM round trips
// per block, ~2.7 blocks/CU can't cover them.
//
// R4 (T4 counted-vmcnt): raw s_barrier + lgkmcnt(0)-only (no vmcnt drain),
// register pipeline deepened to 2 chunks (wreg[2][4], static idx, full
// unroll). Compiler emits *counted* vmcnt for the pack's register deps, so
// chunk c+2 loads stay in flight across the barrier. Everything else
// (load pattern, swizzle, epilogue) is byte-identical to R3.

#define M_TOK 16
#define K_DIM 4096
#define N_OUT 11008

typedef int v4i __attribute__((ext_vector_type(4)));

// ---------------- Kernel 1: per-token quantization of x ----------------
// ws layout: xh[16*4096] | xl[16*4096] | s1[16] | sumx[16]
__global__ __launch_bounds__(256) void quant_x_kernel(
    const float* __restrict__ x, int8_t* __restrict__ xh,
    int8_t* __restrict__ xl, float* __restrict__ s1_out,
    float* __restrict__ sumx_out) {
  const int t = blockIdx.x;      // token
  const int tid = threadIdx.x;   // 256 threads, 16 consecutive elems each
  const float4* xv = (const float4*)(x + (long)t * K_DIM) + tid * 4;

  float vals[16];
  float m = 0.0f, s = 0.0f;
#pragma unroll
  for (int j = 0; j < 4; ++j) {
    float4 f = xv[j];
    vals[j * 4 + 0] = f.x; vals[j * 4 + 1] = f.y;
    vals[j * 4 + 2] = f.z; vals[j * 4 + 3] = f.w;
    m = fmaxf(m, fmaxf(fmaxf(fabsf(f.x), fabsf(f.y)),
                       fmaxf(fabsf(f.z), fabsf(f.w))));
    s += f.x + f.y + f.z + f.w;
  }
#pragma unroll
  for (int off = 32; off > 0; off >>= 1) {
    m = fmaxf(m, __shfl_xor(m, off));
    s += __shfl_xor(s, off);
  }
  __shared__ float lm[4], ls[4];
  const int w = tid >> 6;
  if ((tid & 63) == 0) { lm[w] = m; ls[w] = s; }
  __syncthreads();
  m = fmaxf(fmaxf(lm[0], lm[1]), fmaxf(lm[2], lm[3]));
  s = ls[0] + ls[1] + ls[2] + ls[3];

  const float s1 = (m > 0.0f) ? (m * (1.0f / 127.0f)) : 1.0f;
  const float inv = 1.0f / s1;
  if (tid == 0) { s1_out[t] = s1; sumx_out[t] = s; }

  int hq[16], lq[16];
#pragma unroll
  for (int j = 0; j < 16; ++j) {
    float xf = vals[j];
    float h = rintf(xf * inv);
    h = fminf(fmaxf(h, -127.0f), 127.0f);
    float resid = xf - h * s1;
    float l = rintf(resid * inv * 256.0f);
    l = fminf(fmaxf(l, -128.0f), 127.0f);
    hq[j] = (int)h;
    lq[j] = (int)l;
  }
  int4 hv, lv;
  int* hp = (int*)&hv;
  int* lp = (int*)&lv;
#pragma unroll
  for (int d = 0; d < 4; ++d) {
    uint32_t hw = 0, lw = 0;
#pragma unroll
    for (int j = 0; j < 4; ++j) {
      hw |= (uint32_t)(hq[d * 4 + j] & 0xff) << (8 * j);
      lw |= (uint32_t)(lq[d * 4 + j] & 0xff) << (8 * j);
    }
    hp[d] = (int)hw;
    lp[d] = (int)lw;
  }
  ((int4*)xh)[(long)t * 256 + tid] = hv;
  ((int4*)xl)[(long)t * 256 + tid] = lv;
}

// ---------------- Kernel 2: LDS-staged weight-streaming i8 MFMA GEMM ------
// Grid = 688 blocks x 256 thr (4 waves). Block owns 16 output rows, full K.
// Per 256-k chunk: wave w stages rows 4w..4w+3 (1 KB contiguous per row per
// instruction), packs to int8, writes swizzled LDS; each wave computes its
// K-quarter with one ds_read_b128 + hi/lo MFMA pair. 16 chunks, 2x4KB LDS
// double buffer, raw barrier (no vmcnt drain), 2-chunk register pipeline.
__global__ __launch_bounds__(256) void qgemm_kernel(
    const int* __restrict__ W, const int8_t* __restrict__ xh,
    const int8_t* __restrict__ xl, const float* __restrict__ s1,
    const float* __restrict__ sumx, const float* __restrict__ scale_p,
    const int* __restrict__ zp_p, float* __restrict__ out) {
  const int tid = threadIdx.x;
  const int lane = tid & 63;
  const int w = tid >> 6;          // wave id = K quarter within chunk
  const int obase = blockIdx.x * 16;
  const int n = lane & 15;         // output-row (B col) / token (A row)
  const int g = lane >> 4;         // k sub-group within 64-k window
  const int r0 = w * 4;            // first staged row for this wave

  __shared__ v4i wbuf[2][256];     // [buf][row*16 + slot] packed int8
  __shared__ float red[4][16 * 17];

  // Staging pointers: 1 KB contiguous per row per chunk, lane*16B apart.
  const v4i* Wr0 = (const v4i*)(W + (long)(obase + r0 + 0) * K_DIM) + lane;
  const v4i* Wr1 = (const v4i*)(W + (long)(obase + r0 + 1) * K_DIM) + lane;
  const v4i* Wr2 = (const v4i*)(W + (long)(obase + r0 + 2) * K_DIM) + lane;
  const v4i* Wr3 = (const v4i*)(W + (long)(obase + r0 + 3) * K_DIM) + lane;

  // LDS write index (dword units), XOR-swizzled within each 256B row so the
  // b128 fragment reads spread across all 8 bank-rows.
  int wr_idx[4];
#pragma unroll
  for (int r = 0; r < 4; ++r) {
    const int row = r0 + r;
    wr_idx[r] = row * 64 + (lane ^ ((row & 7) << 2));
  }
  // LDS read index (v4i units): logical slot 4w+g of row n, swizzled.
  const int rd_idx = n * 16 + ((4 * w + g) ^ (n & 7));

  // A fragments (L2-resident x planes): 16B per chunk per plane.
  const v4i* Ah = (const v4i*)xh + (n * 256 + w * 4 + g);
  const v4i* Al = (const v4i*)xl + (n * 256 + w * 4 + g);

  // Prologue: chunks 0 and 1 into the register pipeline; pack chunk 0.
  v4i wreg[2][4];
  wreg[0][0] = Wr0[0];
  wreg[0][1] = Wr1[0];
  wreg[0][2] = Wr2[0];
  wreg[0][3] = Wr3[0];
  wreg[1][0] = Wr0[64];
  wreg[1][1] = Wr1[64];
  wreg[1][2] = Wr2[64];
  wreg[1][3] = Wr3[64];
  {
    uint32_t* wb = (uint32_t*)wbuf[0];
#pragma unroll
    for (int r = 0; r < 4; ++r) {
      v4i q = wreg[0][r];
      uint32_t packed = ((uint32_t)q.x & 0xffu) |
                        (((uint32_t)q.y & 0xffu) << 8) |
                        (((uint32_t)q.z & 0xffu) << 16) |
                        (((uint32_t)q.w & 0xffu) << 24);
      wb[wr_idx[r]] = packed;
    }
  }
  asm volatile("s_waitcnt lgkmcnt(0)" ::: "memory");
  __builtin_amdgcn_s_barrier();

  v4i accH = {0, 0, 0, 0};
  v4i accL = {0, 0, 0, 0};

#pragma unroll
  for (int c = 0; c < 16; ++c) {
    const int cur = c & 1;
    // A fragments for this chunk (L2-hot, counted wait before MFMA).
    v4i ah = Ah[c * 16];
    v4i al = Al[c * 16];
    // Issue chunk c+2 loads; wreg[cur] (chunk c) was packed last iter.
    if (c + 2 < 16) {
      wreg[cur][0] = Wr0[(c + 2) * 64];
      wreg[cur][1] = Wr1[(c + 2) * 64];
      wreg[cur][2] = Wr2[(c + 2) * 64];
      wreg[cur][3] = Wr3[(c + 2) * 64];
    }
    // Pack chunk c+1 into the other LDS buffer (compiler emits a counted
    // vmcnt here: chunk c+2 loads stay in flight across the barrier).
    if (c + 1 < 16) {
      uint32_t* wb = (uint32_t*)wbuf[cur ^ 1];
#pragma unroll
      for (int r = 0; r < 4; ++r) {
        v4i q = wreg[cur ^ 1][r];
        uint32_t packed = ((uint32_t)q.x & 0xffu) |
                          (((uint32_t)q.y & 0xffu) << 8) |
                          (((uint32_t)q.z & 0xffu) << 16) |
                          (((uint32_t)q.w & 0xffu) << 24);
        wb[wr_idx[r]] = packed;
      }
    }
    // Compute chunk c.
    const v4i b = wbuf[cur][rd_idx];
    accH = __builtin_amdgcn_mfma_i32_16x16x64_i8(ah, b, accH, 0, 0, 0);
    accL = __builtin_amdgcn_mfma_i32_16x16x64_i8(al, b, accL, 0, 0, 0);
    // LDS-visibility-only barrier: NO vmcnt drain.
    asm volatile("s_waitcnt lgkmcnt(0)" ::: "memory");
    __builtin_amdgcn_s_barrier();
  }

  // C layout (16x16): col = lane&15 (=o), row = (lane>>4)*4 + reg (=token)
#pragma unroll
  for (int r = 0; r < 4; ++r) {
    float f = (float)accH[r] + (float)accL[r] * (1.0f / 256.0f);
    const int t = g * 4 + r;
    red[w][t * 17 + n] = f;
  }
  __syncthreads();

  const int t = tid >> 4;
  const int col = tid & 15;
  const float sum = red[0][t * 17 + col] + red[1][t * 17 + col] +
                    red[2][t * 17 + col] + red[3][t * 17 + col];
  const float sc = scale_p[0];
  const float zp = (float)zp_p[0];
  const float o = sc * (s1[t] * sum) - sc * zp * sumx[t];
  out[(long)t * N_OUT + obase + col] = o;
}

extern "C" void kernel_launch(void* const* d_in, const int* in_sizes, int n_in,
                              void* d_out, int out_size, void* d_ws,
                              size_t ws_size, hipStream_t stream) {
  const float* x = (const float*)d_in[0];
  const int* Wq = (const int*)d_in[1];          // int inputs come as int32
  const float* scale_p = (const float*)d_in[2];
  const int* zp_p = (const int*)d_in[3];
  float* out = (float*)d_out;

  int8_t* xh = (int8_t*)d_ws;
  int8_t* xl = xh + (long)M_TOK * K_DIM;
  float* s1 = (float*)(xl + (long)M_TOK * K_DIM);
  float* sumx = s1 + M_TOK;

  quant_x_kernel<<<M_TOK, 256, 0, stream>>>(x, xh, xl, s1, sumx);
  qgemm_kernel<<<N_OUT / 16, 256, 0, stream>>>(Wq, xh, xl, s1, sumx, scale_p,
                                               zp_p, out);
}